// Round 12
// baseline (182.996 us; speedup 1.0000x reference)
//
#include <hip/hip_runtime.h>
#include <math.h>

// Problem constants: B=4, T=1024, C=1024, H=16, DH=64
namespace {
constexpr int NB  = 4;
constexpr int NT  = 1024;
constexpr int NC  = 1024;
constexpr int NH  = 16;
constexpr int MT  = NB * NT;   // 4096
}

typedef _Float16 f16x8 __attribute__((ext_vector_type(8)));
typedef float f32x4 __attribute__((ext_vector_type(4)));
typedef int i32x4 __attribute__((ext_vector_type(4)));

__device__ __forceinline__ unsigned sad8(unsigned a, unsigned b, unsigned c) {
  unsigned d;
  asm("v_sad_u8 %0, %1, %2, %3" : "=v"(d) : "v"(a), "v"(b), "v"(c));
  return d;
}

__device__ __forceinline__ unsigned short f16u(float x) {
  _Float16 h = (_Float16)x;
  return __builtin_bit_cast(unsigned short, h);
}

// ---------------- prep (unchanged from R9) ----------------
__global__ __launch_bounds__(256) void k_prep(const float* __restrict__ x,
                                              const float* __restrict__ wq,
                                              const float* __restrict__ wk,
                                              const float* __restrict__ wv,
                                              const float* __restrict__ wo,
                                              unsigned* __restrict__ sgnx,
                                              unsigned* __restrict__ wi8,
                                              float* __restrict__ sumax,
                                              unsigned short* __restrict__ woh) {
  const int bid = blockIdx.x;
  const int tid = threadIdx.x;
  if (bid < 2048) {
    int i8o = bid * 256 + tid;
    const float4* in4 = reinterpret_cast<const float4*>(x);
    float4 v0 = in4[2 * i8o], v1 = in4[2 * i8o + 1];
    float t[8] = {v0.x, v0.y, v0.z, v0.w, v1.x, v1.y, v1.z, v1.w};
    unsigned b[8];
    float s = 0.0f;
#pragma unroll
    for (int j = 0; j < 8; ++j) {
      float tv = tanhf(t[j]);
      s += fabsf(tv);
      b[j] = (tv >= 0.0f) ? 0x01u : 0xFFu;
    }
    uint2 o = {b[0] | (b[1] << 8) | (b[2] << 16) | (b[3] << 24),
               b[4] | (b[5] << 8) | (b[6] << 16) | (b[7] << 24)};
    reinterpret_cast<uint2*>(sgnx)[i8o] = o;
#pragma unroll
    for (int off = 32; off > 0; off >>= 1) s += __shfl_down(s, off, 64);
    __shared__ float ws[4];
    if ((tid & 63) == 0) ws[tid >> 6] = s;
    __syncthreads();
    if (tid == 0) {
      sumax[2 * bid]     = ws[0] + ws[1];
      sumax[2 * bid + 1] = ws[2] + ws[3];
    }
  } else if (bid < 3584) {
    const float* in;
    int local;
    if (bid < 2560)      { in = wq; local = bid - 2048; }
    else if (bid < 3072) { in = wk; local = bid - 2560; }
    else                 { in = wv; local = bid - 3072; }
    unsigned* out = wi8 + ((bid < 2560) ? 0 : (bid < 3072) ? (1024 * 256) : (2048 * 256));
    int i8o = local * 256 + tid;
    const float4* in4 = reinterpret_cast<const float4*>(in);
    float4 v0 = in4[2 * i8o], v1 = in4[2 * i8o + 1];
    float t[8] = {v0.x, v0.y, v0.z, v0.w, v1.x, v1.y, v1.z, v1.w};
    unsigned q[8];
#pragma unroll
    for (int j = 0; j < 8; ++j) {
      int qi = __float2int_rn(tanhf(t[j]) * 1024.0f);
      q[j] = (unsigned)qi & 255u;
    }
    uint2 o = {q[0] | (q[1] << 8) | (q[2] << 16) | (q[3] << 24),
               q[4] | (q[5] << 8) | (q[6] << 16) | (q[7] << 24)};
    reinterpret_cast<uint2*>(out)[i8o] = o;
  } else {
    int i = (bid - 3584) * 256 + tid;
    const float4* in4 = reinterpret_cast<const float4*>(wo);
    float4 v0 = in4[2 * i], v1 = in4[2 * i + 1];
    ushort4 o0 = {f16u(v0.x), f16u(v0.y), f16u(v0.z), f16u(v0.w)};
    ushort4 o1 = {f16u(v1.x), f16u(v1.y), f16u(v1.z), f16u(v1.w)};
    reinterpret_cast<ushort4*>(woh)[2 * i] = o0;
    reinterpret_cast<ushort4*>(woh)[2 * i + 1] = o1;
  }
}

// ---------------- sign-trick projection via i8 MFMA (unchanged from R9) ----------------
__global__ __launch_bounds__(256, 2) void k_signproj(const unsigned* __restrict__ sgnx,
                                                     const unsigned* __restrict__ wi8,
                                                     const float* __restrict__ sumax,
                                                     const float* __restrict__ g0,
                                                     const float* __restrict__ g1,
                                                     const float* __restrict__ g2,
                                                     unsigned* __restrict__ qq,
                                                     unsigned* __restrict__ kq,
                                                     unsigned short* __restrict__ vh) {
  __shared__ unsigned Ash[128][36];
  __shared__ unsigned Bsh[128][36];

  const int tid = threadIdx.x;
  const int n0 = blockIdx.x * 128;
  const int m0 = blockIdx.y * 128;
  const int lane = tid & 63;
  const int wvI = tid >> 6;
  const int wr = wvI >> 1, wc = wvI & 1;
  const int lr = lane & 15, lq = lane >> 4;

  i32x4 acc[4][4] = {};

  const unsigned* A = sgnx + (size_t)m0 * 256;
  const unsigned* Bm = wi8 + (size_t)n0 * 256;

  for (int ks = 0; ks < 8; ++ks) {
    __syncthreads();
#pragma unroll
    for (int p = 0; p < 4; ++p) {
      int idx = tid + p * 256;
      int r = idx >> 3;
      int q4 = (idx & 7) * 4;
      *reinterpret_cast<uint4*>(&Ash[r][q4]) =
          *reinterpret_cast<const uint4*>(A + (size_t)r * 256 + ks * 32 + q4);
      *reinterpret_cast<uint4*>(&Bsh[r][q4]) =
          *reinterpret_cast<const uint4*>(Bm + (size_t)r * 256 + ks * 32 + q4);
    }
    __syncthreads();

#pragma unroll
    for (int kk = 0; kk < 2; ++kk) {
      i32x4 af[4], bf[4];
#pragma unroll
      for (int f = 0; f < 4; ++f) {
        uint4 au = *reinterpret_cast<const uint4*>(&Ash[wr * 64 + f * 16 + lr][kk * 16 + lq * 4]);
        af[f] = __builtin_bit_cast(i32x4, au);
        uint4 bu = *reinterpret_cast<const uint4*>(&Bsh[wc * 64 + f * 16 + lr][kk * 16 + lq * 4]);
        bf[f] = __builtin_bit_cast(i32x4, bu);
      }
#pragma unroll
      for (int fm = 0; fm < 4; ++fm)
#pragma unroll
        for (int fn = 0; fn < 4; ++fn)
          acc[fm][fn] = __builtin_amdgcn_mfma_i32_16x16x64_i8(af[fm], bf[fn], acc[fm][fn], 0, 0, 0);
    }
  }

  const int z = n0 >> 10;
  const int nloc = n0 & 1023;
  const int hl = nloc >> 6;
  const int bI = m0 >> 10;
  const int tloc0 = (m0 & 1023) + wr * 64;
  const float* G = (z == 0) ? g0 : ((z == 1) ? g1 : g2);
  const int h = hl + wc;

  float sx[4][4];
#pragma unroll
  for (int fm = 0; fm < 4; ++fm) {
    float4 sv = *reinterpret_cast<const float4*>(sumax + m0 + wr * 64 + fm * 16 + lq * 4);
    sx[fm][0] = sv.x; sx[fm][1] = sv.y; sx[fm][2] = sv.z; sx[fm][3] = sv.w;
  }

  if (z < 2) {
    unsigned* dst = (z == 0) ? qq : kq;
    const int sh = (lr & 3) * 8;
#pragma unroll
    for (int fn = 0; fn < 4; ++fn) {
      float gn = G[nloc + wc * 64 + fn * 16 + lr];
      int txw = (fn * 16 + lr) >> 2;
#pragma unroll
      for (int fm = 0; fm < 4; ++fm) {
#pragma unroll
        for (int reg = 0; reg < 4; ++reg) {
          float accf = (float)acc[fm][fn][reg];
          float dist = (sx[fm][reg] - accf * (1.0f / 1024.0f)) * (1.0f / 1024.0f);
          float val = (0.5f - dist) * gn;
          unsigned p = ((unsigned)fminf(fmaxf(fmaf(val, 64.0f, 128.5f), 0.0f), 255.0f)) << sh;
          p |= __shfl_xor(p, 1, 64);
          p |= __shfl_xor(p, 2, 64);
          if ((lr & 3) == 0) {
            int t = tloc0 + fm * 16 + lq * 4 + reg;
            dst[(((size_t)(bI * NH + h)) * NT + t) * 16 + txw] = p;
          }
        }
      }
    }
  } else {
#pragma unroll
    for (int fn = 0; fn < 4; ++fn) {
      int dh = fn * 16 + lr;
      float gn = G[nloc + wc * 64 + dh];
#pragma unroll
      for (int fm = 0; fm < 4; ++fm) {
        int t0 = tloc0 + fm * 16 + lq * 4;
        ushort4 o;
#pragma unroll
        for (int reg = 0; reg < 4; ++reg) {
          float accf = (float)acc[fm][fn][reg];
          float dist = (sx[fm][reg] - accf * (1.0f / 1024.0f)) * (1.0f / 1024.0f);
          float val = (0.5f - dist) * gn;
          ((unsigned short*)&o)[reg] = f16u(val);
        }
        *reinterpret_cast<ushort4*>(vh + ((size_t)(bI * NH + h) * 64 + dh) * NT + t0) = o;
      }
    }
  }
}

// ---------------- fused Student-t attention v8: Q-in-regs, 4q x 8k, 512 threads ----------------
// 128q x 128k tile. Q staged LDS->regs once (64 VGPR); kt loop reads only K (2 b128/du).
__global__ __launch_bounds__(512, 4) void k_attn8(const unsigned* __restrict__ qq,
                                                  const unsigned* __restrict__ kq,
                                                  const unsigned short* __restrict__ vh,
                                                  const float* __restrict__ gamma,
                                                  const float* __restrict__ rho,
                                                  unsigned short* __restrict__ att_h) {
  const int qt = blockIdx.x;  // 0..7 (128-row q tiles)
  const int h  = blockIdx.y;
  const int b  = blockIdx.z;

  __shared__ unsigned Qs[16][132];  // [du][qrow] -- used once for Q reg staging
  __shared__ unsigned Ks[16][132];  // [du][split-quad col 0..127]
  __shared__ unsigned Vt[64][68];   // [d][kpair 0..63]
  __shared__ unsigned Ws[128][72];  // [qrow][kpair f16x2, XOR-bit2 swizzled]
  __shared__ float Inv[128];

  const int tid = threadIdx.x;
  const int lane = tid & 63;
  const int lr = lane & 15, lq = lane >> 4;
  const int w16 = (tid >> 6) * 16;   // wave 0..7 -> q rows w16..+15
  const int ty = tid >> 4;   // 0..31 -> q rows ty*4..+3
  const int tx = tid & 15;   // 0..15 -> k rows 8tx..8tx+7 (split-quad)

  const float g  = log1pf(expf(gamma[h])) + 1e-4f;
  const float rr = log1pf(expf(rho[h])) + 1e-4f;
  const float gs = g * (1.0f / (64.0f * 64.0f));

  // stage Q: global -> LDS transposed (1 uint4/thread), then LDS -> regs (16 b128)
  const unsigned* qbase = qq + (((size_t)(b * NH + h)) * NT + qt * 128) * 16;
  {
    int r = tid >> 2;             // 0..127
    int c4 = (tid & 3) * 4;       // 0,4,8,12
    uint4 v = *reinterpret_cast<const uint4*>(qbase + (size_t)r * 16 + c4);
    Qs[c4 + 0][r] = v.x; Qs[c4 + 1][r] = v.y;
    Qs[c4 + 2][r] = v.z; Qs[c4 + 3][r] = v.w;
  }
  __syncthreads();
  uint4 qr[16];
#pragma unroll
  for (int du = 0; du < 16; ++du)
    qr[du] = *reinterpret_cast<const uint4*>(&Qs[du][ty * 4]);

  f32x4 acc[4] = {};
  float wsum[4] = {0.f, 0.f, 0.f, 0.f};

  const unsigned* kbh = kq + (((size_t)(b * NH + h)) * NT) * 16;
  const unsigned* v32 = reinterpret_cast<const unsigned*>(vh + ((size_t)(b * NH + h) * 64) * NT);

  for (int kt = 0; kt < 8; ++kt) {
    __syncthreads();  // prev PV done with Ws/Vt; prev SAD done with Ks; Q regs ready
    // stage K: 128 rows x 16 u32 (1 uint4/thread), transposed split-quad
    {
      const unsigned* kbase = kbh + (size_t)(kt * 128) * 16;
      int r = tid >> 2;           // 0..127
      int c4 = (tid & 3) * 4;
      uint4 v = *reinterpret_cast<const uint4*>(kbase + (size_t)r * 16 + c4);
      int cc = ((r & 7) < 4) ? ((r >> 3) * 4 + (r & 3)) : (64 + (r >> 3) * 4 + (r & 3));
      Ks[c4 + 0][cc] = v.x; Ks[c4 + 1][cc] = v.y;
      Ks[c4 + 2][cc] = v.z; Ks[c4 + 3][cc] = v.w;
    }
    // stage V: 64 d x 64 u32 (2 uint4/thread)
#pragma unroll
    for (int p = 0; p < 2; ++p) {
      int idx = tid + p * 512;
      int d = idx >> 4;           // 0..63
      int q4 = (idx & 15) * 4;    // 0..60
      uint4 v = *reinterpret_cast<const uint4*>(v32 + (size_t)d * 512 + kt * 64 + q4);
      *reinterpret_cast<uint4*>(&Vt[d][q4]) = v;
    }
    __syncthreads();

    // SAD distances: 4q x 8k per thread; Q from regs, K 2 b128/du
    unsigned dl[4][8] = {};
#pragma unroll 8
    for (int du = 0; du < 16; ++du) {
      uint4 k0 = *reinterpret_cast<const uint4*>(&Ks[du][tx * 4]);
      uint4 k1 = *reinterpret_cast<const uint4*>(&Ks[du][64 + tx * 4]);
      unsigned qa[4] = {qr[du].x, qr[du].y, qr[du].z, qr[du].w};
      unsigned ka[8] = {k0.x, k0.y, k0.z, k0.w, k1.x, k1.y, k1.z, k1.w};
#pragma unroll
      for (int i = 0; i < 4; ++i)
#pragma unroll
        for (int j = 0; j < 8; ++j) dl[i][j] = sad8(qa[i], ka[j], dl[i][j]);
    }

    // Student-t weights -> Ws (uint4 writes, XOR-bit2 swizzle by row parity)
#pragma unroll
    for (int i = 0; i < 4; ++i) {
      int qrow = ty * 4 + i;
      float w0[8];
#pragma unroll
      for (int j = 0; j < 8; ++j)
        w0[j] = exp2f(-rr * log2f(fmaf(gs, (float)dl[i][j], 1.0f)));
      wsum[i] += ((w0[0] + w0[1]) + (w0[2] + w0[3])) + ((w0[4] + w0[5]) + (w0[6] + w0[7]));
      uint4 pk;
      pk.x = (unsigned)f16u(w0[0]) | ((unsigned)f16u(w0[1]) << 16);
      pk.y = (unsigned)f16u(w0[2]) | ((unsigned)f16u(w0[3]) << 16);
      pk.z = (unsigned)f16u(w0[4]) | ((unsigned)f16u(w0[5]) << 16);
      pk.w = (unsigned)f16u(w0[6]) | ((unsigned)f16u(w0[7]) << 16);
      *reinterpret_cast<uint4*>(&Ws[qrow][(tx * 4) ^ ((qrow & 1) << 2)]) = pk;
    }
    __syncthreads();

    // PV: per wave O[16q x 64d] += W^T V, 16 MFMA per kt
#pragma unroll
    for (int kk = 0; kk < 4; ++kk) {
      int r = w16 + lr;
      uint4 au = *reinterpret_cast<const uint4*>(&Ws[r][(kk * 16 + lq * 4) ^ ((r & 1) << 2)]);
      f16x8 af = __builtin_bit_cast(f16x8, au);
#pragma unroll
      for (int nt = 0; nt < 4; ++nt) {
        uint4 bu = *reinterpret_cast<const uint4*>(&Vt[nt * 16 + lr][kk * 16 + lq * 4]);
        f16x8 bf = __builtin_bit_cast(f16x8, bu);
        acc[nt] = __builtin_amdgcn_mfma_f32_16x16x32_f16(af, bf, acc[nt], 0, 0, 0);
      }
    }
  }

  // wsum: reduce across the 16 tx lanes (lane bits 0..3)
#pragma unroll
  for (int i = 0; i < 4; ++i) {
    float s = wsum[i];
    s += __shfl_xor(s, 1, 64);
    s += __shfl_xor(s, 2, 64);
    s += __shfl_xor(s, 4, 64);
    s += __shfl_xor(s, 8, 64);
    if (tx == 0) Inv[ty * 4 + i] = 1.0f / (s + 1e-6f);
  }
  __syncthreads();

  {
    float iv[4];
#pragma unroll
    for (int r = 0; r < 4; ++r) iv[r] = Inv[w16 + lq * 4 + r];
    const size_t rowbase = (size_t)(b * NT + qt * 128 + w16 + lq * 4);
    const int colbase = h * 64 + lr;
#pragma unroll
    for (int nt = 0; nt < 4; ++nt)
#pragma unroll
      for (int r = 0; r < 4; ++r)
        att_h[(rowbase + r) * NC + colbase + nt * 16] = f16u(acc[nt][r] * iv[r]);
  }
}

// ---------------- f16 MFMA output GEMM (unchanged) ----------------
__global__ __launch_bounds__(256) void k_gemm16(const unsigned short* __restrict__ A,
                                                const unsigned short* __restrict__ Bw,
                                                const float* __restrict__ bias,
                                                float* __restrict__ Out) {
  __shared__ unsigned Ash[128 * 20];
  __shared__ unsigned Bsh[128 * 20];

  const int tid = threadIdx.x;
  const int m0 = blockIdx.y * 128;
  const int n0 = blockIdx.x * 128;
  const int lane = tid & 63;
  const int wv = tid >> 6;
  const int wr = wv >> 1, wc = wv & 1;
  const int lr = lane & 15, lq = lane >> 4;

  f32x4 acc[4][4] = {};

  const unsigned* A32 = reinterpret_cast<const unsigned*>(A);
  const unsigned* B32 = reinterpret_cast<const unsigned*>(Bw);

  for (int ks = 0; ks < 32; ++ks) {
    __syncthreads();
#pragma unroll
    for (int p = 0; p < 2; ++p) {
      int idx = tid + p * 256;
      int r = idx >> 2, q = idx & 3;
      uint4 av = *reinterpret_cast<const uint4*>(A32 + (size_t)(m0 + r) * 512 + ks * 16 + q * 4);
      *reinterpret_cast<uint4*>(&Ash[r * 20 + q * 4]) = av;
      uint4 bv = *reinterpret_cast<const uint4*>(B32 + (size_t)(n0 + r) * 512 + ks * 16 + q * 4);
      *reinterpret_cast<uint4*>(&Bsh[r * 20 + q * 4]) = bv;
    }
    __syncthreads();

    f16x8 af[4], bf[4];
#pragma unroll
    for (int f = 0; f < 4; ++f) {
      uint4 au = *reinterpret_cast<const uint4*>(&Ash[(wr * 64 + f * 16 + lr) * 20 + lq * 4]);
      af[f] = __builtin_bit_cast(f16x8, au);
      uint4 bu = *reinterpret_cast<const uint4*>(&Bsh[(wc * 64 + f * 16 + lr) * 20 + lq * 4]);
      bf[f] = __builtin_bit_cast(f16x8, bu);
    }
#pragma unroll
    for (int fm = 0; fm < 4; ++fm)
#pragma unroll
      for (int fn = 0; fn < 4; ++fn)
        acc[fm][fn] = __builtin_amdgcn_mfma_f32_16x16x32_f16(af[fm], bf[fn], acc[fm][fn], 0, 0, 0);
  }

#pragma unroll
  for (int fn = 0; fn < 4; ++fn) {
    int col = n0 + wc * 64 + fn * 16 + lr;
    float bb = bias[col];
#pragma unroll
    for (int fm = 0; fm < 4; ++fm) {
      int rowb = m0 + wr * 64 + fm * 16 + lq * 4;
#pragma unroll
      for (int r = 0; r < 4; ++r)
        Out[(size_t)(rowb + r) * NC + col] = acc[fm][fn][r] + bb;
    }
  }
}

extern "C" void kernel_launch(void* const* d_in, const int* in_sizes, int n_in,
                              void* d_out, int out_size, void* d_ws, size_t ws_size,
                              hipStream_t stream) {
  (void)in_sizes; (void)n_in; (void)out_size; (void)ws_size;
  const float* x     = (const float*)d_in[0];
  const float* wq_w  = (const float*)d_in[1];
  const float* wq_g  = (const float*)d_in[2];
  const float* wk_w  = (const float*)d_in[3];
  const float* wk_g  = (const float*)d_in[4];
  const float* wv_w  = (const float*)d_in[5];
  const float* wv_g  = (const float*)d_in[6];
  const float* wo_w  = (const float*)d_in[7];
  const float* wo_b  = (const float*)d_in[8];
  const float* gamma = (const float*)d_in[9];
  const float* rho   = (const float*)d_in[10];
  float* out = (float*)d_out;

  // workspace layout:
  unsigned* sgnx = (unsigned*)d_ws;                          // 4MB
  unsigned* wi8  = sgnx + (size_t)MT * 256;                  // 3MB
  float* sumax   = (float*)(wi8 + 3072ull * 256);            // 16KB
  unsigned* qqhm = (unsigned*)(sumax + MT);                  // 4MB
  unsigned* kqhm = qqhm + (size_t)NB * NH * NT * 16;         // 4MB
  unsigned short* vhdm = (unsigned short*)(kqhm + (size_t)NB * NH * NT * 16);  // 8MB
  unsigned short* atth = vhdm + (size_t)NB * NH * 64 * NT;   // 8MB
  unsigned short* woh  = atth + (size_t)MT * NC;             // 2MB

  // 1. prep: x -> signs + row-sums; w -> i8; wo -> f16
  k_prep<<<4096, 256, 0, stream>>>(x, wq_w, wk_w, wv_w, wo_w, sgnx, wi8, sumax, woh);

  // 2. q/k/v projections via sign-trick i8 MFMA GEMM
  k_signproj<<<dim3(3072 / 128, MT / 128), 256, 0, stream>>>(sgnx, wi8, sumax,
                                                             wq_g, wk_g, wv_g,
                                                             qqhm, kqhm, vhdm);

  // 3. fused Student-t attention v8 (Q-in-regs, 4q x 8k, 512 threads)
  k_attn8<<<dim3(NT / 128, NH, NB), 512, 0, stream>>>(qqhm, kqhm, vhdm, gamma, rho, atth);

  // 4. output projection via f16 MFMA GEMM
  k_gemm16<<<dim3(NC / 128, MT / 128, 1), 256, 0, stream>>>(atth, woh, wo_b, out);
}

// Round 14
// 126.362 us; speedup vs baseline: 1.4482x; 1.4482x over previous
//
#include <hip/hip_runtime.h>
#include <math.h>

// Problem constants: B=4, T=1024, C=1024, H=16, DH=64
namespace {
constexpr int NB  = 4;
constexpr int NT  = 1024;
constexpr int NC  = 1024;
constexpr int NH  = 16;
constexpr int MT  = NB * NT;   // 4096
}

typedef _Float16 f16x8 __attribute__((ext_vector_type(8)));
typedef float f32x4 __attribute__((ext_vector_type(4)));
typedef int i32x4 __attribute__((ext_vector_type(4)));

__device__ __forceinline__ unsigned sad8(unsigned a, unsigned b, unsigned c) {
  unsigned d;
  asm("v_sad_u8 %0, %1, %2, %3" : "=v"(d) : "v"(a), "v"(b), "v"(c));
  return d;
}

// raw HW log2/exp2 (domain-safe: arg in [1,2.7] / [-3.1,0]; skips libm guards)
__device__ __forceinline__ float rlog2(float x) {
  float r; asm("v_log_f32 %0, %1" : "=v"(r) : "v"(x)); return r;
}
__device__ __forceinline__ float rexp2(float x) {
  float r; asm("v_exp_f32 %0, %1" : "=v"(r) : "v"(x)); return r;
}
// 2x f32 -> packed f16 (RTZ) in one instruction
__device__ __forceinline__ unsigned pk16(float a, float b) {
  auto h = __builtin_amdgcn_cvt_pkrtz(a, b);   // __fp16 ext_vector(2)
  return __builtin_bit_cast(unsigned, h);
}

__device__ __forceinline__ unsigned short f16u(float x) {
  _Float16 h = (_Float16)x;
  return __builtin_bit_cast(unsigned short, h);
}

// ---------------- prep (unchanged from R9) ----------------
__global__ __launch_bounds__(256) void k_prep(const float* __restrict__ x,
                                              const float* __restrict__ wq,
                                              const float* __restrict__ wk,
                                              const float* __restrict__ wv,
                                              const float* __restrict__ wo,
                                              unsigned* __restrict__ sgnx,
                                              unsigned* __restrict__ wi8,
                                              float* __restrict__ sumax,
                                              unsigned short* __restrict__ woh) {
  const int bid = blockIdx.x;
  const int tid = threadIdx.x;
  if (bid < 2048) {
    int i8o = bid * 256 + tid;
    const float4* in4 = reinterpret_cast<const float4*>(x);
    float4 v0 = in4[2 * i8o], v1 = in4[2 * i8o + 1];
    float t[8] = {v0.x, v0.y, v0.z, v0.w, v1.x, v1.y, v1.z, v1.w};
    unsigned b[8];
    float s = 0.0f;
#pragma unroll
    for (int j = 0; j < 8; ++j) {
      float tv = tanhf(t[j]);
      s += fabsf(tv);
      b[j] = (tv >= 0.0f) ? 0x01u : 0xFFu;
    }
    uint2 o = {b[0] | (b[1] << 8) | (b[2] << 16) | (b[3] << 24),
               b[4] | (b[5] << 8) | (b[6] << 16) | (b[7] << 24)};
    reinterpret_cast<uint2*>(sgnx)[i8o] = o;
#pragma unroll
    for (int off = 32; off > 0; off >>= 1) s += __shfl_down(s, off, 64);
    __shared__ float ws[4];
    if ((tid & 63) == 0) ws[tid >> 6] = s;
    __syncthreads();
    if (tid == 0) {
      sumax[2 * bid]     = ws[0] + ws[1];
      sumax[2 * bid + 1] = ws[2] + ws[3];
    }
  } else if (bid < 3584) {
    const float* in;
    int local;
    if (bid < 2560)      { in = wq; local = bid - 2048; }
    else if (bid < 3072) { in = wk; local = bid - 2560; }
    else                 { in = wv; local = bid - 3072; }
    unsigned* out = wi8 + ((bid < 2560) ? 0 : (bid < 3072) ? (1024 * 256) : (2048 * 256));
    int i8o = local * 256 + tid;
    const float4* in4 = reinterpret_cast<const float4*>(in);
    float4 v0 = in4[2 * i8o], v1 = in4[2 * i8o + 1];
    float t[8] = {v0.x, v0.y, v0.z, v0.w, v1.x, v1.y, v1.z, v1.w};
    unsigned q[8];
#pragma unroll
    for (int j = 0; j < 8; ++j) {
      int qi = __float2int_rn(tanhf(t[j]) * 1024.0f);
      q[j] = (unsigned)qi & 255u;
    }
    uint2 o = {q[0] | (q[1] << 8) | (q[2] << 16) | (q[3] << 24),
               q[4] | (q[5] << 8) | (q[6] << 16) | (q[7] << 24)};
    reinterpret_cast<uint2*>(out)[i8o] = o;
  } else {
    int i = (bid - 3584) * 256 + tid;
    const float4* in4 = reinterpret_cast<const float4*>(wo);
    float4 v0 = in4[2 * i], v1 = in4[2 * i + 1];
    ushort4 o0 = {f16u(v0.x), f16u(v0.y), f16u(v0.z), f16u(v0.w)};
    ushort4 o1 = {f16u(v1.x), f16u(v1.y), f16u(v1.z), f16u(v1.w)};
    reinterpret_cast<ushort4*>(woh)[2 * i] = o0;
    reinterpret_cast<ushort4*>(woh)[2 * i + 1] = o1;
  }
}

// ---------------- sign-trick projection via i8 MFMA (unchanged from R9) ----------------
__global__ __launch_bounds__(256, 2) void k_signproj(const unsigned* __restrict__ sgnx,
                                                     const unsigned* __restrict__ wi8,
                                                     const float* __restrict__ sumax,
                                                     const float* __restrict__ g0,
                                                     const float* __restrict__ g1,
                                                     const float* __restrict__ g2,
                                                     unsigned* __restrict__ qq,
                                                     unsigned* __restrict__ kq,
                                                     unsigned short* __restrict__ vh) {
  __shared__ unsigned Ash[128][36];
  __shared__ unsigned Bsh[128][36];

  const int tid = threadIdx.x;
  const int n0 = blockIdx.x * 128;
  const int m0 = blockIdx.y * 128;
  const int lane = tid & 63;
  const int wvI = tid >> 6;
  const int wr = wvI >> 1, wc = wvI & 1;
  const int lr = lane & 15, lq = lane >> 4;

  i32x4 acc[4][4] = {};

  const unsigned* A = sgnx + (size_t)m0 * 256;
  const unsigned* Bm = wi8 + (size_t)n0 * 256;

  for (int ks = 0; ks < 8; ++ks) {
    __syncthreads();
#pragma unroll
    for (int p = 0; p < 4; ++p) {
      int idx = tid + p * 256;
      int r = idx >> 3;
      int q4 = (idx & 7) * 4;
      *reinterpret_cast<uint4*>(&Ash[r][q4]) =
          *reinterpret_cast<const uint4*>(A + (size_t)r * 256 + ks * 32 + q4);
      *reinterpret_cast<uint4*>(&Bsh[r][q4]) =
          *reinterpret_cast<const uint4*>(Bm + (size_t)r * 256 + ks * 32 + q4);
    }
    __syncthreads();

#pragma unroll
    for (int kk = 0; kk < 2; ++kk) {
      i32x4 af[4], bf[4];
#pragma unroll
      for (int f = 0; f < 4; ++f) {
        uint4 au = *reinterpret_cast<const uint4*>(&Ash[wr * 64 + f * 16 + lr][kk * 16 + lq * 4]);
        af[f] = __builtin_bit_cast(i32x4, au);
        uint4 bu = *reinterpret_cast<const uint4*>(&Bsh[wc * 64 + f * 16 + lr][kk * 16 + lq * 4]);
        bf[f] = __builtin_bit_cast(i32x4, bu);
      }
#pragma unroll
      for (int fm = 0; fm < 4; ++fm)
#pragma unroll
        for (int fn = 0; fn < 4; ++fn)
          acc[fm][fn] = __builtin_amdgcn_mfma_i32_16x16x64_i8(af[fm], bf[fn], acc[fm][fn], 0, 0, 0);
    }
  }

  const int z = n0 >> 10;
  const int nloc = n0 & 1023;
  const int hl = nloc >> 6;
  const int bI = m0 >> 10;
  const int tloc0 = (m0 & 1023) + wr * 64;
  const float* G = (z == 0) ? g0 : ((z == 1) ? g1 : g2);
  const int h = hl + wc;

  float sx[4][4];
#pragma unroll
  for (int fm = 0; fm < 4; ++fm) {
    float4 sv = *reinterpret_cast<const float4*>(sumax + m0 + wr * 64 + fm * 16 + lq * 4);
    sx[fm][0] = sv.x; sx[fm][1] = sv.y; sx[fm][2] = sv.z; sx[fm][3] = sv.w;
  }

  if (z < 2) {
    unsigned* dst = (z == 0) ? qq : kq;
    const int sh = (lr & 3) * 8;
#pragma unroll
    for (int fn = 0; fn < 4; ++fn) {
      float gn = G[nloc + wc * 64 + fn * 16 + lr];
      int txw = (fn * 16 + lr) >> 2;
#pragma unroll
      for (int fm = 0; fm < 4; ++fm) {
#pragma unroll
        for (int reg = 0; reg < 4; ++reg) {
          float accf = (float)acc[fm][fn][reg];
          float dist = (sx[fm][reg] - accf * (1.0f / 1024.0f)) * (1.0f / 1024.0f);
          float val = (0.5f - dist) * gn;
          unsigned p = ((unsigned)fminf(fmaxf(fmaf(val, 64.0f, 128.5f), 0.0f), 255.0f)) << sh;
          p |= __shfl_xor(p, 1, 64);
          p |= __shfl_xor(p, 2, 64);
          if ((lr & 3) == 0) {
            int t = tloc0 + fm * 16 + lq * 4 + reg;
            dst[(((size_t)(bI * NH + h)) * NT + t) * 16 + txw] = p;
          }
        }
      }
    }
  } else {
#pragma unroll
    for (int fn = 0; fn < 4; ++fn) {
      int dh = fn * 16 + lr;
      float gn = G[nloc + wc * 64 + dh];
#pragma unroll
      for (int fm = 0; fm < 4; ++fm) {
        int t0 = tloc0 + fm * 16 + lq * 4;
        ushort4 o;
#pragma unroll
        for (int reg = 0; reg < 4; ++reg) {
          float accf = (float)acc[fm][fn][reg];
          float dist = (sx[fm][reg] - accf * (1.0f / 1024.0f)) * (1.0f / 1024.0f);
          float val = (0.5f - dist) * gn;
          ((unsigned short*)&o)[reg] = f16u(val);
        }
        *reinterpret_cast<ushort4*>(vh + ((size_t)(bI * NH + h) * 64 + dh) * NT + t0) = o;
      }
    }
  }
}

// ---------------- fused Student-t attention v7.2: 128q x 128k, 512 threads ----------------
// v7 structure (best measured) + raw v_log/v_exp weights + cvt_pkrtz packing.
__global__ __launch_bounds__(512, 4) void k_attn7(const unsigned* __restrict__ qq,
                                                  const unsigned* __restrict__ kq,
                                                  const unsigned short* __restrict__ vh,
                                                  const float* __restrict__ gamma,
                                                  const float* __restrict__ rho,
                                                  unsigned short* __restrict__ att_h) {
  const int qt = blockIdx.x;  // 0..7 (128-row q tiles)
  const int h  = blockIdx.y;
  const int b  = blockIdx.z;

  __shared__ unsigned Qs[16][132];  // [du][qrow 0..127]
  __shared__ unsigned Ks[16][132];  // [du][split-quad col 0..127]
  __shared__ unsigned Vt[64][68];   // [d][kpair 0..63]
  __shared__ unsigned Ws[128][72];  // [qrow][kpair f16x2, XOR-bit2 swizzled]
  __shared__ float Inv[128];

  const int tid = threadIdx.x;
  const int lane = tid & 63;
  const int lr = lane & 15, lq = lane >> 4;
  const int w16 = (tid >> 6) * 16;   // wave 0..7 -> q rows w16..+15
  const int ty = tid >> 5;   // 0..15 -> q rows ty*8..+7
  const int tx = tid & 31;   // 0..31 -> logical k rows 4tx..4tx+3

  const float g  = log1pf(expf(gamma[h])) + 1e-4f;
  const float rr = log1pf(expf(rho[h])) + 1e-4f;
  const float gs = g * (1.0f / (64.0f * 64.0f));
  const float nrr = -rr;

  // stage Q once: 128 rows x 16 u32, transposed (1 uint4/thread)
  const unsigned* qbase = qq + (((size_t)(b * NH + h)) * NT + qt * 128) * 16;
  {
    int r = tid >> 2;             // 0..127
    int c4 = (tid & 3) * 4;       // 0,4,8,12
    uint4 v = *reinterpret_cast<const uint4*>(qbase + (size_t)r * 16 + c4);
    Qs[c4 + 0][r] = v.x; Qs[c4 + 1][r] = v.y;
    Qs[c4 + 2][r] = v.z; Qs[c4 + 3][r] = v.w;
  }

  f32x4 acc[4] = {};
  float wsum[8] = {0.f, 0.f, 0.f, 0.f, 0.f, 0.f, 0.f, 0.f};

  const unsigned* kbh = kq + (((size_t)(b * NH + h)) * NT) * 16;
  const unsigned* v32 = reinterpret_cast<const unsigned*>(vh + ((size_t)(b * NH + h) * 64) * NT);

  for (int kt = 0; kt < 8; ++kt) {
    __syncthreads();  // prev PV done with Ws/Vt; prev SAD done with Ks; Qs ready (kt=0)
    // stage K: 128 rows x 16 u32 (1 uint4/thread), transposed split-quad
    {
      const unsigned* kbase = kbh + (size_t)(kt * 128) * 16;
      int r = tid >> 2;           // 0..127
      int c4 = (tid & 3) * 4;
      uint4 v = *reinterpret_cast<const uint4*>(kbase + (size_t)r * 16 + c4);
      int cc = ((r & 7) < 4) ? ((r >> 3) * 4 + (r & 3)) : (64 + (r >> 3) * 4 + (r & 3));
      Ks[c4 + 0][cc] = v.x; Ks[c4 + 1][cc] = v.y;
      Ks[c4 + 2][cc] = v.z; Ks[c4 + 3][cc] = v.w;
    }
    // stage V: 64 d x 64 u32 (2 uint4/thread)
#pragma unroll
    for (int p = 0; p < 2; ++p) {
      int idx = tid + p * 512;
      int d = idx >> 4;           // 0..63
      int q4 = (idx & 15) * 4;    // 0..60
      uint4 v = *reinterpret_cast<const uint4*>(v32 + (size_t)d * 512 + kt * 64 + q4);
      *reinterpret_cast<uint4*>(&Vt[d][q4]) = v;
    }
    __syncthreads();

    // SAD distances: 8q x 4k per thread
    const int kbase_col = ((tx & 1) << 6) + (tx >> 1) * 4;
    unsigned dl[8][4] = {};
#pragma unroll 8
    for (int du = 0; du < 16; ++du) {
      uint4 q0 = *reinterpret_cast<const uint4*>(&Qs[du][ty * 8]);
      uint4 q1 = *reinterpret_cast<const uint4*>(&Qs[du][ty * 8 + 4]);
      uint4 kv = *reinterpret_cast<const uint4*>(&Ks[du][kbase_col]);
      unsigned qa[8] = {q0.x, q0.y, q0.z, q0.w, q1.x, q1.y, q1.z, q1.w};
      unsigned ka[4] = {kv.x, kv.y, kv.z, kv.w};
#pragma unroll
      for (int i = 0; i < 8; ++i)
#pragma unroll
        for (int j = 0; j < 4; ++j) dl[i][j] = sad8(qa[i], ka[j], dl[i][j]);
    }

    // Student-t weights -> Ws (raw v_log/v_exp; cvt_pkrtz pack; XOR-bit2 swizzle)
#pragma unroll
    for (int i = 0; i < 8; ++i) {
      int qrow = ty * 8 + i;
      float w0[4];
#pragma unroll
      for (int j = 0; j < 4; ++j)
        w0[j] = rexp2(nrr * rlog2(fmaf(gs, (float)dl[i][j], 1.0f)));
      wsum[i] += (w0[0] + w0[1]) + (w0[2] + w0[3]);
      uint2 pk = {pk16(w0[0], w0[1]), pk16(w0[2], w0[3])};
      *reinterpret_cast<uint2*>(&Ws[qrow][(tx * 2) ^ ((qrow & 1) << 2)]) = pk;
    }
    __syncthreads();

    // PV: per wave O[16q x 64d] += W^T V, 16 MFMA per kt
#pragma unroll
    for (int kk = 0; kk < 4; ++kk) {
      int r = w16 + lr;
      uint4 au = *reinterpret_cast<const uint4*>(&Ws[r][(kk * 16 + lq * 4) ^ ((r & 1) << 2)]);
      f16x8 af = __builtin_bit_cast(f16x8, au);
#pragma unroll
      for (int nt = 0; nt < 4; ++nt) {
        uint4 bu = *reinterpret_cast<const uint4*>(&Vt[nt * 16 + lr][kk * 16 + lq * 4]);
        f16x8 bf = __builtin_bit_cast(f16x8, bu);
        acc[nt] = __builtin_amdgcn_mfma_f32_16x16x32_f16(af, bf, acc[nt], 0, 0, 0);
      }
    }
  }

  // wsum: reduce across the 32 tx lanes (stays within 32-lane half-wave)
#pragma unroll
  for (int i = 0; i < 8; ++i) {
    float s = wsum[i];
    s += __shfl_xor(s, 1, 64);
    s += __shfl_xor(s, 2, 64);
    s += __shfl_xor(s, 4, 64);
    s += __shfl_xor(s, 8, 64);
    s += __shfl_xor(s, 16, 64);
    if (tx == 0) Inv[ty * 8 + i] = 1.0f / (s + 1e-6f);
  }
  __syncthreads();

  {
    float iv[4];
#pragma unroll
    for (int r = 0; r < 4; ++r) iv[r] = Inv[w16 + lq * 4 + r];
    const size_t rowbase = (size_t)(b * NT + qt * 128 + w16 + lq * 4);
    const int colbase = h * 64 + lr;
#pragma unroll
    for (int nt = 0; nt < 4; ++nt)
#pragma unroll
      for (int r = 0; r < 4; ++r)
        att_h[(rowbase + r) * NC + colbase + nt * 16] = f16u(acc[nt][r] * iv[r]);
  }
}

// ---------------- f16 MFMA output GEMM (unchanged) ----------------
__global__ __launch_bounds__(256) void k_gemm16(const unsigned short* __restrict__ A,
                                                const unsigned short* __restrict__ Bw,
                                                const float* __restrict__ bias,
                                                float* __restrict__ Out) {
  __shared__ unsigned Ash[128 * 20];
  __shared__ unsigned Bsh[128 * 20];

  const int tid = threadIdx.x;
  const int m0 = blockIdx.y * 128;
  const int n0 = blockIdx.x * 128;
  const int lane = tid & 63;
  const int wv = tid >> 6;
  const int wr = wv >> 1, wc = wv & 1;
  const int lr = lane & 15, lq = lane >> 4;

  f32x4 acc[4][4] = {};

  const unsigned* A32 = reinterpret_cast<const unsigned*>(A);
  const unsigned* B32 = reinterpret_cast<const unsigned*>(Bw);

  for (int ks = 0; ks < 32; ++ks) {
    __syncthreads();
#pragma unroll
    for (int p = 0; p < 2; ++p) {
      int idx = tid + p * 256;
      int r = idx >> 2, q = idx & 3;
      uint4 av = *reinterpret_cast<const uint4*>(A32 + (size_t)(m0 + r) * 512 + ks * 16 + q * 4);
      *reinterpret_cast<uint4*>(&Ash[r * 20 + q * 4]) = av;
      uint4 bv = *reinterpret_cast<const uint4*>(B32 + (size_t)(n0 + r) * 512 + ks * 16 + q * 4);
      *reinterpret_cast<uint4*>(&Bsh[r * 20 + q * 4]) = bv;
    }
    __syncthreads();

    f16x8 af[4], bf[4];
#pragma unroll
    for (int f = 0; f < 4; ++f) {
      uint4 au = *reinterpret_cast<const uint4*>(&Ash[(wr * 64 + f * 16 + lr) * 20 + lq * 4]);
      af[f] = __builtin_bit_cast(f16x8, au);
      uint4 bu = *reinterpret_cast<const uint4*>(&Bsh[(wc * 64 + f * 16 + lr) * 20 + lq * 4]);
      bf[f] = __builtin_bit_cast(f16x8, bu);
    }
#pragma unroll
    for (int fm = 0; fm < 4; ++fm)
#pragma unroll
      for (int fn = 0; fn < 4; ++fn)
        acc[fm][fn] = __builtin_amdgcn_mfma_f32_16x16x32_f16(af[fm], bf[fn], acc[fm][fn], 0, 0, 0);
  }

#pragma unroll
  for (int fn = 0; fn < 4; ++fn) {
    int col = n0 + wc * 64 + fn * 16 + lr;
    float bb = bias[col];
#pragma unroll
    for (int fm = 0; fm < 4; ++fm) {
      int rowb = m0 + wr * 64 + fm * 16 + lq * 4;
#pragma unroll
      for (int r = 0; r < 4; ++r)
        Out[(size_t)(rowb + r) * NC + col] = acc[fm][fn][r] + bb;
    }
  }
}

extern "C" void kernel_launch(void* const* d_in, const int* in_sizes, int n_in,
                              void* d_out, int out_size, void* d_ws, size_t ws_size,
                              hipStream_t stream) {
  (void)in_sizes; (void)n_in; (void)out_size; (void)ws_size;
  const float* x     = (const float*)d_in[0];
  const float* wq_w  = (const float*)d_in[1];
  const float* wq_g  = (const float*)d_in[2];
  const float* wk_w  = (const float*)d_in[3];
  const float* wk_g  = (const float*)d_in[4];
  const float* wv_w  = (const float*)d_in[5];
  const float* wv_g  = (const float*)d_in[6];
  const float* wo_w  = (const float*)d_in[7];
  const float* wo_b  = (const float*)d_in[8];
  const float* gamma = (const float*)d_in[9];
  const float* rho   = (const float*)d_in[10];
  float* out = (float*)d_out;

  // workspace layout:
  unsigned* sgnx = (unsigned*)d_ws;                          // 4MB
  unsigned* wi8  = sgnx + (size_t)MT * 256;                  // 3MB
  float* sumax   = (float*)(wi8 + 3072ull * 256);            // 16KB
  unsigned* qqhm = (unsigned*)(sumax + MT);                  // 4MB
  unsigned* kqhm = qqhm + (size_t)NB * NH * NT * 16;         // 4MB
  unsigned short* vhdm = (unsigned short*)(kqhm + (size_t)NB * NH * NT * 16);  // 8MB
  unsigned short* atth = vhdm + (size_t)NB * NH * 64 * NT;   // 8MB
  unsigned short* woh  = atth + (size_t)MT * NC;             // 2MB

  // 1. prep: x -> signs + row-sums; w -> i8; wo -> f16
  k_prep<<<4096, 256, 0, stream>>>(x, wq_w, wk_w, wv_w, wo_w, sgnx, wi8, sumax, woh);

  // 2. q/k/v projections via sign-trick i8 MFMA GEMM
  k_signproj<<<dim3(3072 / 128, MT / 128), 256, 0, stream>>>(sgnx, wi8, sumax,
                                                             wq_g, wk_g, wv_g,
                                                             qqhm, kqhm, vhdm);

  // 3. fused Student-t attention v7.2 (raw-trans weights, pkrtz pack)
  k_attn7<<<dim3(NT / 128, NH, NB), 512, 0, stream>>>(qqhm, kqhm, vhdm, gamma, rho, atth);

  // 4. output projection via f16 MFMA GEMM
  k_gemm16<<<dim3(NC / 128, MT / 128, 1), 256, 0, stream>>>(atth, woh, wo_b, out);
}